// Round 5
// baseline (119.833 us; speedup 1.0000x reference)
//
#include <hip/hip_runtime.h>
#include <hip/hip_bf16.h>
#include <hip/hip_fp8.h>
#include <math.h>

#define BROWS 4096
#define DIM   512
#define YEMB_B 2097152   // 4096*512 bytes, offset of emb rows in Yq (fp8)
#define TSTRIDE 191      // tile stride (tiles are 192 wide, overlap by 1)
#define NT 22            // tiles per dim; FULL grid now: 22*22 tiles x 2 halves

typedef float f32x4 __attribute__((ext_vector_type(4)));

// ---------------------------------------------------------------------------
// prep4: wave-per-row, no barriers. 8192 rows (low then emb), 4 rows/block.
// L2-normalize -> fp8 e4m3 row in Yq; s=sum(y^2), r=sum(y) from f32 y.
// (verified R12-R19: absmax 0.0)
// ---------------------------------------------------------------------------
__global__ __launch_bounds__(256) void prep4_kernel(
    const float* __restrict__ low, const float* __restrict__ emb,
    unsigned char* __restrict__ Yq,
    float* __restrict__ s_l, float* __restrict__ r_l,
    float* __restrict__ s_e, float* __restrict__ r_e,
    float* __restrict__ out) {
  const int tid = threadIdx.x;
  const int lane = tid & 63, wid = tid >> 6;
  const int rid = blockIdx.x * 4 + wid;          // 0..8191
  if (blockIdx.x == 0 && tid == 0) out[0] = 0.f;

  const bool is_low = (rid < BROWS);
  const int row = is_low ? rid : rid - BROWS;
  const float* x = (is_low ? low : emb) + (size_t)row * DIM;

  const float4 v0 = ((const float4*)x)[lane * 2];
  const float4 v1 = ((const float4*)x)[lane * 2 + 1];

  float ss = v0.x * v0.x + v0.y * v0.y + v0.z * v0.z + v0.w * v0.w +
             v1.x * v1.x + v1.y * v1.y + v1.z * v1.z + v1.w * v1.w;
#pragma unroll
  for (int o = 1; o < 64; o <<= 1) ss += __shfl_xor(ss, o, 64);
  const float inv = 1.0f / fmaxf(sqrtf(ss), 1e-12f);

  float y[8] = {v0.x * inv, v0.y * inv, v0.z * inv, v0.w * inv,
                v1.x * inv, v1.y * inv, v1.z * inv, v1.w * inv};

  union { unsigned char b[8]; unsigned long long u; } pk;
  float sv = 0.f, rv = 0.f;
#pragma unroll
  for (int i = 0; i < 8; ++i) {
    pk.b[i] = __hip_fp8_e4m3(y[i]).__x;   // OCP e4m3fn, HW RNE
    sv += y[i] * y[i];
    rv += y[i];
  }
  ((unsigned long long*)(Yq + (size_t)rid * 512))[lane] = pk.u;

#pragma unroll
  for (int o = 1; o < 64; o <<= 1) {
    sv += __shfl_xor(sv, o, 64);
    rv += __shfl_xor(rv, o, 64);
  }
  if (lane == 0) {
    (is_low ? s_l : s_e)[row] = sv;
    (is_low ? r_l : r_e)[row] = rv;
  }
}

// ---------------------------------------------------------------------------
// R21 (resubmit: round 4's bench never acquired a GPU).
// Epilogue-first redesign (R19 post-mortem: VALU-heavy epilogue ~70%
// of fused time; K-loop schedule changes were optimizing the 30%).
//  * FULL grid (22x22 tiles x 2 col-halves = 968 blocks): every (i, j-pair)
//    term computed exactly once as a DIRECT term; pass2/hand_t deleted.
//  * MFMA operands SWAPPED (col-panel is first operand): D row-dim (reg) = j,
//    lane&15 = i. Neighbor-in-j = register-adjacent (75% free, 25% 1 shfl).
//  * Low matrix: no distances. sign(dl1-dl2) = sign(cL[j] - 2(G1-G2));
//    per-column cL precomputed (clamp-drop safe: q<0 only at i==j).
//  * Term identity: coeff*(de2-de1) = sign(Dl)*x + |x|, x = de2-de1.
//  * All s/r gathers -> small LDS prestage (aE per-row; bE, cL per-col).
// K-loop machinery byte-identical to R19 (verified): BK=64, 8 rounds,
// dbuf 2x38,912 B, counted vmcnt, same staging/swizzle/frag addressing.
// LDS total ~79.5 KB -> 2 blocks/CU.
// ---------------------------------------------------------------------------
__global__ __launch_bounds__(256, 2) void fused_sym_kernel(
    const unsigned char* __restrict__ Yq,
    const float* __restrict__ s_l, const float* __restrict__ r_l,
    const float* __restrict__ s_e, const float* __restrict__ r_e,
    float* __restrict__ out) {
  __shared__ __align__(16) long lds_l[9728];   // 2 x 38,912 B staging
  __shared__ __align__(16) float aE[192];      // s_e[i]+2e-6 r_e[i]+epst
  __shared__ __align__(16) float bE[120];      // s_e[j]-2e-6 r_e[j]
  __shared__ __align__(16) float cL[120];      // ql(i,j)-ql(i,j+1) j-const
  __shared__ float sred[4];

  // decode: blockIdx = 2*(br*NT+bc) + half  (full grid)
  const int b2 = blockIdx.x >> 1;
  const int half = blockIdx.x & 1;
  const int br = b2 / NT;
  const int bc = b2 % NT;

  const int tid = threadIdx.x;
  const int lane = tid & 63;
  const int wid = tid >> 6;          // 0..3
  const int wr = wid;                // rows 48*wr..48*wr+47
  const int quad = lane >> 4, cpos = lane & 15;
  const int r0 = br * TSTRIDE;
  const int cB = bc * TSTRIDE + half * 96;   // block's first global col
  const int tcbase = half * 96;              // block's first tile-local col
  const float epst = (float)DIM * 1e-6f * 1e-6f;

  // ---- prestage j/i-side constants into LDS (before STAGE(0) so the
  // counted-vmcnt arithmetic in the K-loop stays valid) ----
  if (tid < 192) {
    const int gi = min(r0 + tid, BROWS - 1);
    aE[tid] = s_e[gi] + 2e-6f * r_e[gi] + epst;
  }
  if (tid < 116) {
    const int gj = min(cB + tid, BROWS - 1);
    const int gj1 = min(cB + tid + 1, BROWS - 1);
    bE[tid] = s_e[gj] - 2e-6f * r_e[gj];
    cL[tid] = (s_l[gj] - s_l[gj1]) - 2e-6f * (r_l[gj] - r_l[gj1]);
  }

  // ---- staging global offsets: 2432 slots of 16B/round, 10 per thread
  // (threads >=128 do 9). Identical to R19 (verified). ----
  int goff[10];
#pragma unroll
  for (int s = 0; s < 10; ++s) {
    const int c = tid + 256 * s;        // 0..2559 (>=2432 unused)
    const int rp = c >> 3, cc = c & 7;
    int seg, rpl;
    if (rp < 96)       { seg = 0; rpl = rp;       }
    else if (rp < 192) { seg = 1; rpl = rp - 96;  }
    else if (rp < 248) { seg = 2; rpl = rp - 192; }
    else               { seg = 3; rpl = rp - 248; }
    const int rloc = 2 * rpl + (cc >> 2);
    const int gch = (cc & 3) ^ (rpl & 3);
    int base;
    if (seg == 0)      base = min(r0 + rloc, BROWS - 1) * 512;
    else if (seg == 1) base = YEMB_B + min(r0 + rloc, BROWS - 1) * 512;
    else if (seg == 2) base = min(cB + rloc, BROWS - 1) * 512;
    else               base = YEMB_B + min(cB + rloc, BROWS - 1) * 512;
    goff[s] = base + (gch << 4);
  }

  auto STAGE = [&](int t, int b) {
    const int k0 = t * 64;
#pragma unroll
    for (int s = 0; s < 10; ++s) {
      if (s < 9 || tid < 128)
        __builtin_amdgcn_global_load_lds(
            (const __attribute__((address_space(1))) void*)(Yq + goff[s] + k0),
            (__attribute__((address_space(3))) void*)(
                ((char*)lds_l) + b * 38912 + (tid + 256 * s) * 16),
            16, 0, 0);
    }
  };

  // ---- frag addressing (bytes -> long indices); identical to R19 ----
  const int RaH = (48 * wr + cpos) >> 1;
  const int s3a = RaH & 3;
  const int aoff = RaH * 128 + (cpos & 1) * 64 + (quad & 1) * 8;
  const int s3b = (cpos >> 1) & 3;
  const int boff = (cpos >> 1) * 128 + (cpos & 1) * 64 + (quad & 1) * 8;
  const int iaL = aoff >> 3;               // row-panel low  (B operand now)
  const int iaE = (12288 + aoff) >> 3;     // row-panel emb
  const int ibL = (24576 + boff) >> 3;     // col-panel low  (A operand now)
  const int ibE = (31744 + boff) >> 3;     // col-panel emb

  f32x4 accl[7][3], acce[7][3];
#pragma unroll
  for (int jb = 0; jb < 7; ++jb)
#pragma unroll
    for (int ib = 0; ib < 3; ++ib) {
      accl[jb][ib] = (f32x4)(0.f);
      acce[jb][ib] = (f32x4)(0.f);
    }

  STAGE(0, 0);   // prologue prefetch

  for (int t = 0; t < 8; ++t) {
    if (t < 7) STAGE(t + 1, (t + 1) & 1);
    if (t == 7)       asm volatile("s_waitcnt vmcnt(0)" ::: "memory");
    else if (wid < 2) asm volatile("s_waitcnt vmcnt(10)" ::: "memory");
    else              asm volatile("s_waitcnt vmcnt(9)" ::: "memory");
    __builtin_amdgcn_s_barrier();
    __builtin_amdgcn_sched_barrier(0);

    const int bo = (t & 1) * 4864;   // buffer offset in longs
#pragma unroll
    for (int kk = 0; kk < 2; ++kk) {
      const int q = 2 * kk + (quad >> 1);          // 16B chunk 0..3
      const int qa2 = ((q ^ s3a) << 1);            // chunk offset in longs
      const int qb2 = ((q ^ s3b) << 1);
      {  // low matrix: A = col-panel (j -> reg dim), B = row-panel (i -> lane)
        long a[7], b[3];
#pragma unroll
        for (int jb = 0; jb < 7; ++jb) a[jb] = lds_l[bo + ibL + qb2 + jb * 128];
#pragma unroll
        for (int ib = 0; ib < 3; ++ib) b[ib] = lds_l[bo + iaL + qa2 + ib * 128];
        __builtin_amdgcn_s_setprio(1);
#pragma unroll
        for (int jb = 0; jb < 7; ++jb)
#pragma unroll
          for (int ib = 0; ib < 3; ++ib)
            accl[jb][ib] = __builtin_amdgcn_mfma_f32_16x16x32_fp8_fp8(
                a[jb], b[ib], accl[jb][ib], 0, 0, 0);
        __builtin_amdgcn_s_setprio(0);
      }
      {  // emb matrix
        long a[7], b[3];
#pragma unroll
        for (int jb = 0; jb < 7; ++jb) a[jb] = lds_l[bo + ibE + qb2 + jb * 128];
#pragma unroll
        for (int ib = 0; ib < 3; ++ib) b[ib] = lds_l[bo + iaE + qa2 + ib * 128];
        __builtin_amdgcn_s_setprio(1);
#pragma unroll
        for (int jb = 0; jb < 7; ++jb)
#pragma unroll
          for (int ib = 0; ib < 3; ++ib)
            acce[jb][ib] = __builtin_amdgcn_mfma_f32_16x16x32_fp8_fp8(
                a[jb], b[ib], acce[jb][ib], 0, 0, 0);
        __builtin_amdgcn_s_setprio(0);
      }
    }
    __builtin_amdgcn_sched_barrier(0);
    __builtin_amdgcn_s_barrier();
    __builtin_amdgcn_sched_barrier(0);
  }

  // ---- epilogue: j in reg dim. acc[jb][ib][r] -> (j = cB+16jb+4quad+r,
  // i = r0+48wr+16ib+cpos). Rolling deJ/deN per ib; term identity. ----
  float sum = 0.f;

#pragma unroll
  for (int ib = 0; ib < 3; ++ib) {
    const int irow = 48 * wr + 16 * ib + cpos;
    const int gi = r0 + irow;
    const bool rowok = (irow <= TSTRIDE - 1) && (gi <= BROWS - 2);
    const float ai = aE[irow];

    float deJ[4], glJ[4];
    {
      const float4 bj = ((const float4*)bE)[quad];        // jb=0
#pragma unroll
      for (int r = 0; r < 4; ++r) {
        deJ[r] = sqrtf(fmaxf(ai + bj[r] - 2.f * acce[0][ib][r], 0.f));
        glJ[r] = accl[0][ib][r];
      }
    }

#pragma unroll
    for (int jb = 0; jb < 6; ++jb) {
      // next column block (jb+1): de and raw G
      const float4 bn = ((const float4*)bE)[4 * (jb + 1) + quad];
      float deN[4], glN[4];
#pragma unroll
      for (int r = 0; r < 4; ++r) {
        deN[r] = sqrtf(fmaxf(ai + bn[r] - 2.f * acce[jb + 1][ib][r], 0.f));
        glN[r] = accl[jb + 1][ib][r];
      }
      // cross-lane values for the r=3 pair
      const float deq = __shfl(deJ[0], (lane + 16) & 63, 64);  // quad+1, r0
      const float dec = __shfl(deN[0], lane & 15, 64);         // quad0, jb+1
      const float glq = __shfl(glJ[0], (lane + 16) & 63, 64);
      const float glc = __shfl(glN[0], lane & 15, 64);
      const float de2r3 = (quad < 3) ? deq : dec;
      const float gl2r3 = (quad < 3) ? glq : glc;

      const float4 cl = ((const float4*)cL)[4 * jb + quad];
#pragma unroll
      for (int r = 0; r < 4; ++r) {
        const float de1 = deJ[r];
        const float de2 = (r < 3) ? deJ[r + 1] : de2r3;
        const float g2 = (r < 3) ? glJ[r + 1] : gl2r3;
        const float x = de2 - de1;
        const float Dl = cl[r] - 2.f * (glJ[r] - g2);  // ql1 - ql2
        const float tterm = fabsf(x) +
                            (Dl > 0.f ? x : (Dl < 0.f ? -x : 0.f));
        const int jcol = tcbase + 16 * jb + 4 * quad + r;
        const int gj = cB + 16 * jb + 4 * quad + r;
        if (rowok && jcol <= TSTRIDE - 1 && gj <= BROWS - 3) sum += tterm;
      }
#pragma unroll
      for (int r = 0; r < 4; ++r) { deJ[r] = deN[r]; glJ[r] = glN[r]; }
    }
  }

  // ---- reduce + atomic ----
#pragma unroll
  for (int o = 32; o; o >>= 1) sum += __shfl_down(sum, o, 64);
  if (lane == 0) sred[wid] = sum;
  __syncthreads();
  if (tid == 0) {
    const float scale = 1.0f / ((float)(BROWS - 1) * (float)(BROWS - 2));
    float t = 0.f;
#pragma unroll
    for (int w = 0; w < 4; ++w) t += sred[w];
    atomicAdd(out, t * scale);
  }
}

// ===========================================================================
extern "C" void kernel_launch(void* const* d_in, const int* in_sizes, int n_in,
                              void* d_out, int out_size, void* d_ws,
                              size_t ws_size, hipStream_t stream) {
  const float* low = (const float*)d_in[0];
  const float* emb = (const float*)d_in[1];
  float* out = (float*)d_out;

  // ws: Yq (2*4096*512 fp8 = 4 MB) then s_l, r_l, s_e, r_e (4096 f32 each)
  unsigned char* Yq = (unsigned char*)d_ws;
  float* s_l = (float*)(Yq + 2 * (size_t)BROWS * DIM);
  float* r_l = s_l + BROWS;
  float* s_e = r_l + BROWS;
  float* r_e = s_e + BROWS;

  prep4_kernel<<<2 * BROWS / 4, 256, 0, stream>>>(low, emb, Yq, s_l, r_l, s_e, r_e, out);
  fused_sym_kernel<<<NT * NT * 2, 256, 0, stream>>>(Yq, s_l, r_l, s_e, r_e, out);
}